// Round 4
// baseline (143.351 us; speedup 1.0000x reference)
//
#include <hip/hip_runtime.h>

// Problem dims (fixed by reference)
#define Bb  8
#define Mm  4096
#define Nn  64
#define Ff  9
#define Ss  5
#define NRr 3

// Per-atom table record: 48 floats (192 B), per (b,n), in per-BLOCK private ws slice:
//  [0]=bc0 [1]=p0 [2]=bc1 [3]=p1 [4]=bc2 [5]=p2 [6,7]=pad   (bc = b*log2 e)
//  [8+f*4 .. 11+f*4] = A_f, ux, uy, uz    f = 0..8  (A = a*|c|, u = c/|c|)
constexpr int REC = 48;
constexpr int MT  = 64;    // m per block (= lane)
constexpr int PAD = 193;   // 192+1 floats/row -> 2 lanes/bank max (free on gfx950)

__global__ __launch_bounds__(256)
void HarmonicGenAMD_25786983645325_kernel(
    const float* __restrict__ dv,     // [B,M,N,3]
    const float* __restrict__ coef,   // [B,N,F,3]
    const int*   __restrict__ labels, // [B,N]
    const float* __restrict__ pa,
    const float* __restrict__ pb,
    const float* __restrict__ pp,
    float*       __restrict__ out,    // [B,M]
    float*       __restrict__ tbl_w,  // ws, write view  (per-block slice)
    const float* __restrict__ tbl_r)  // ws, read view   (same memory; barrier orders)
{
    __shared__ __align__(16) float dvs[MT * PAD];   // 49408 B
    __shared__ float red[256];

    const int tid = threadIdx.x;
    const int blk = blockIdx.x;       // 0..511
    const int b   = blk >> 6;
    const int m0  = (blk & 63) * MT;

    // ---- issue dv m-tile staging first (fills VMEM queue): 64 x 192 floats ----
    const float* g = dv + ((size_t)b * Mm + m0) * (Nn * 3);
    for (int i = tid * 4; i < MT * Nn * 3; i += 256 * 4) {
        const int row = i / 192;
        const int col = i - row * 192;
        const float4 v = *(const float4*)(g + (size_t)row * 192 + col);
        float* d = &dvs[row * PAD + col];   // odd stride: conflict-free ds_write_b32 x4
        d[0] = v.x; d[1] = v.y; d[2] = v.z; d[3] = v.w;
    }

    // ---- phase 1: per-block private atom table into ws (overlaps with staging) ----
    float* myt = tbl_w + (size_t)blk * (Nn * REC);
    if (tid < Nn) {                         // headers: one atom per thread
        const int s = labels[b * Nn + tid];
        float4 h0, h1;
        h0.x = pb[s * NRr + 0] * 1.44269504088896340736f;  h0.y = pp[s * NRr + 0];
        h0.z = pb[s * NRr + 1] * 1.44269504088896340736f;  h0.w = pp[s * NRr + 1];
        h1.x = pb[s * NRr + 2] * 1.44269504088896340736f;  h1.y = pp[s * NRr + 2];
        h1.z = 0.0f; h1.w = 0.0f;
        *(float4*)(myt + tid * REC + 0) = h0;
        *(float4*)(myt + tid * REC + 4) = h1;
    }
    for (int i = tid; i < Nn * Ff; i += 256) {   // quads: one (n,f) per thread
        const int n = i / Ff;
        const int f = i - n * Ff;
        const int j = f / 3;
        const int s = labels[b * Nn + n];
        const float* c = coef + ((size_t)(b * Nn + n) * Ff + f) * 3;
        const float cx = c[0], cy = c[1], cz = c[2];
        const float cn  = sqrtf(cx * cx + cy * cy + cz * cz);
        const float inv = 1.0f / fmaxf(cn, 1e-12f);
        float4 q;
        q.x = pa[s * NRr + j] * cn;
        q.y = cx * inv; q.z = cy * inv; q.w = cz * inv;
        *(float4*)(myt + n * REC + 8 + f * 4) = q;
    }
    __threadfence();      // drain write-through stores to L2 (scalar-cache visibility)
    __syncthreads();      // one barrier covers LDS staging + table stores

    // ---- phase 2: lane = m_local, wave = 16-atom slice; table via s_load path ----
    const int lane  = tid & 63;
    const int nbase = __builtin_amdgcn_readfirstlane((tid >> 6) * 16);
    const float* tb   = tbl_r + (size_t)blk * (Nn * REC) + nbase * REC;
    const float* drow = &dvs[lane * PAD + nbase * 3];

    float acc = 0.0f;
#pragma unroll 4
    for (int t = 0; t < 16; ++t) {
        const float* rec = tb + t * REC;        // uniform (SGPR base + const offset)
        const float x = drow[t * 3 + 0];
        const float y = drow[t * 3 + 1];
        const float z = drow[t * 3 + 2];
        const float r2   = __fmaf_rn(x, x, __fmaf_rn(y, y, z * z));
        const float rinv = __builtin_amdgcn_rsqf(r2);          // 1/r
        const float r    = r2 * rinv;
        const float l2r  = 0.5f * __builtin_amdgcn_logf(r2);   // log2(r)
        const float dnx = x * rinv, dny = y * rinv, dnz = z * rinv;

        const float4 h0 = *(const float4*)(rec);       // bc0,p0,bc1,p1
        const float2 h1 = *(const float2*)(rec + 4);   // bc2,p2
        float ek[3];
        ek[0] = __builtin_amdgcn_exp2f(__fmaf_rn(h0.y, l2r, -h0.x * r));
        ek[1] = __builtin_amdgcn_exp2f(__fmaf_rn(h0.w, l2r, -h0.z * r));
        ek[2] = __builtin_amdgcn_exp2f(__fmaf_rn(h1.y, l2r, -h1.x * r));
#pragma unroll
        for (int f = 0; f < Ff; ++f) {
            const float4 e = *(const float4*)(rec + 8 + f * 4);  // A, ux, uy, uz
            const float c = __fmaf_rn(dnx, e.y, __fmaf_rn(dny, e.z, dnz * e.w));
            float q;
            if      (f % 3 == 0) q = c;                                    // P1
            else if (f % 3 == 1) q = __fmaf_rn(1.5f * c, c, -0.5f);        // P2
            else                 q = c * __fmaf_rn(2.5f * c, c, -1.5f);    // P3
            acc = __fmaf_rn(e.x * ek[f / 3], q, acc);
        }
    }

    // ---- cross-wave reduction (4 waves), coalesced store ----
    red[tid] = acc;
    __syncthreads();
    if (tid < MT) {
        out[(size_t)b * Mm + m0 + tid] =
            red[tid] + red[MT + tid] + red[2 * MT + tid] + red[3 * MT + tid];
    }
}

extern "C" void kernel_launch(void* const* d_in, const int* in_sizes, int n_in,
                              void* d_out, int out_size, void* d_ws, size_t ws_size,
                              hipStream_t stream) {
    const float* dv   = (const float*)d_in[0];
    const float* coef = (const float*)d_in[1];
    const int*   lab  = (const int*)d_in[2];
    const float* pa   = (const float*)d_in[3];
    const float* pb   = (const float*)d_in[4];
    const float* pp   = (const float*)d_in[5];
    float* out = (float*)d_out;
    float* ws  = (float*)d_ws;   // 512 blocks x 12 KiB private table slices = 6 MiB

    dim3 grid(Bb * (Mm / MT));  // 512 blocks, single launch
    HarmonicGenAMD_25786983645325_kernel<<<grid, 256, 0, stream>>>(
        dv, coef, lab, pa, pb, pp, out, ws, (const float*)ws);
}

// Round 5
// 84.778 us; speedup vs baseline: 1.6909x; 1.6909x over previous
//
#include <hip/hip_runtime.h>

// Problem dims (fixed by reference)
#define Bb  8
#define Mm  4096
#define Nn  64
#define Ff  9
#define Ss  5
#define NRr 3

// Per-atom LDS record: 48 floats (192 B):
//  [0]=bc0 [1]=p0 [2]=bc1 [3]=p1 [4]=bc2 [5]=p2 [6,7]=pad   (bc = b*log2 e)
//  [8+f*4 .. 11+f*4] = A_f, ux, uy, uz   (A = a*|c|, u = c/|c|)
constexpr int REC = 48;
constexpr int MT  = 32;   // m per block
constexpr int STR = 195;  // LDS row stride: reads 2-way, writes <=6-way (cheap)

__global__ __launch_bounds__(256, 4)
void HarmonicGenAMD_25786983645325_kernel(
    const float* __restrict__ dv,     // [B,M,N,3]
    const float* __restrict__ coef,   // [B,N,F,3]
    const int*   __restrict__ labels, // [B,N]
    const float* __restrict__ pa,
    const float* __restrict__ pb,
    const float* __restrict__ pp,
    float*       __restrict__ out)    // [B,M]
{
    __shared__ __align__(16) float dvs[MT * STR];    // 24960 B
    __shared__ __align__(16) float tabs[Nn * REC];   // 12288 B
    __shared__ float red[128];                       // 512 B  -> total ~37.8 KB: 4 blk/CU

    const int tid = threadIdx.x;
    const int blk = blockIdx.x;        // 0..1023
    const int b   = blk >> 7;
    const int m0  = (blk & 127) * MT;

    // ---- stage dv tile: 32 rows x 192 floats, coalesced global float4 ----
    const float* g = dv + ((size_t)b * Mm + m0) * (Nn * 3);
#pragma unroll
    for (int it = 0; it < 6; ++it) {
        const int i   = it * 1024 + tid * 4;     // 6144 floats
        const int row = i / 192;
        const int col = i - row * 192;
        const float4 v = *(const float4*)(g + row * 192 + col);
        float* d = &dvs[row * STR + col];
        d[0] = v.x; d[1] = v.y; d[2] = v.z; d[3] = v.w;
    }

    // ---- build atom table in LDS (overlaps staging loads) ----
    if (tid < Nn) {
        const int s = labels[b * Nn + tid];
        float4 h0, h1;
        h0.x = pb[s * NRr + 0] * 1.44269504088896340736f;  h0.y = pp[s * NRr + 0];
        h0.z = pb[s * NRr + 1] * 1.44269504088896340736f;  h0.w = pp[s * NRr + 1];
        h1.x = pb[s * NRr + 2] * 1.44269504088896340736f;  h1.y = pp[s * NRr + 2];
        h1.z = 0.0f; h1.w = 0.0f;
        *(float4*)(&tabs[tid * REC + 0]) = h0;
        *(float4*)(&tabs[tid * REC + 4]) = h1;
    }
    for (int i = tid; i < Nn * Ff; i += 256) {
        const int n = i / Ff;
        const int f = i - n * Ff;
        const int j = f / 3;
        const int s = labels[b * Nn + n];
        const float* c = coef + ((size_t)(b * Nn + n) * Ff + f) * 3;
        const float cx = c[0], cy = c[1], cz = c[2];
        const float cn  = sqrtf(cx * cx + cy * cy + cz * cz);
        const float inv = 1.0f / fmaxf(cn, 1e-12f);
        float4 q;
        q.x = pa[s * NRr + j] * cn;
        q.y = cx * inv; q.z = cy * inv; q.w = cz * inv;
        *(float4*)(&tabs[n * REC + 8 + f * 4]) = q;
    }
    __syncthreads();

    // ---- main loop: DS-only (in-order lgkm -> pipelines). lane = (half, m). ----
    // Wave w covers atoms [w*16, w*16+16): per iter the two half-waves take
    // adjacent atoms -> table ds_read_b128 has 2 addrs/wave (free broadcast).
    const int lane = tid & 63;
    const int w    = tid >> 6;
    const int m    = lane & 31;
    const int h    = lane >> 5;
    const float* drow = &dvs[m * STR];

    float acc = 0.0f;
#pragma unroll 2
    for (int t = 0; t < 8; ++t) {
        const int n = w * 16 + t * 2 + h;
        const float* rec = &tabs[n * REC];
        const float x = drow[n * 3 + 0];
        const float y = drow[n * 3 + 1];
        const float z = drow[n * 3 + 2];
        const float r2   = __fmaf_rn(x, x, __fmaf_rn(y, y, z * z));
        const float rinv = __builtin_amdgcn_rsqf(r2);          // 1/r
        const float r    = r2 * rinv;
        const float l2r  = 0.5f * __builtin_amdgcn_logf(r2);   // log2(r)
        const float dnx = x * rinv, dny = y * rinv, dnz = z * rinv;

        const float4 h0 = *(const float4*)(rec);       // bc0,p0,bc1,p1
        const float2 h1 = *(const float2*)(rec + 4);   // bc2,p2
        float ek[3];
        ek[0] = __builtin_amdgcn_exp2f(__fmaf_rn(h0.y, l2r, -h0.x * r));
        ek[1] = __builtin_amdgcn_exp2f(__fmaf_rn(h0.w, l2r, -h0.z * r));
        ek[2] = __builtin_amdgcn_exp2f(__fmaf_rn(h1.y, l2r, -h1.x * r));
#pragma unroll
        for (int f = 0; f < Ff; ++f) {
            const float4 e = *(const float4*)(rec + 8 + f * 4);  // A, ux, uy, uz
            const float c = __fmaf_rn(dnx, e.y, __fmaf_rn(dny, e.z, dnz * e.w));
            float q;
            if      (f % 3 == 0) q = c;                                    // P1
            else if (f % 3 == 1) q = __fmaf_rn(1.5f * c, c, -0.5f);        // P2
            else                 q = c * __fmaf_rn(2.5f * c, c, -1.5f);    // P3
            acc = __fmaf_rn(e.x * ek[f / 3], q, acc);
        }
    }

    // ---- reduce: halves within wave, then 4 waves via LDS ----
    acc += __shfl_down(acc, 32, 64);
    if (h == 0) red[w * MT + m] = acc;
    __syncthreads();
    if (tid < MT) {
        out[(size_t)b * Mm + m0 + tid] =
            red[tid] + red[MT + tid] + red[2 * MT + tid] + red[3 * MT + tid];
    }
}

extern "C" void kernel_launch(void* const* d_in, const int* in_sizes, int n_in,
                              void* d_out, int out_size, void* d_ws, size_t ws_size,
                              hipStream_t stream) {
    const float* dv   = (const float*)d_in[0];
    const float* coef = (const float*)d_in[1];
    const int*   lab  = (const int*)d_in[2];
    const float* pa   = (const float*)d_in[3];
    const float* pb   = (const float*)d_in[4];
    const float* pp   = (const float*)d_in[5];
    float* out = (float*)d_out;

    dim3 grid(Bb * (Mm / MT));  // 1024 blocks = 4/CU, single launch, no ws
    HarmonicGenAMD_25786983645325_kernel<<<grid, 256, 0, stream>>>(
        dv, coef, lab, pa, pb, pp, out);
}